// Round 5
// baseline (1141.236 us; speedup 1.0000x reference)
//
#include <hip/hip_runtime.h>

// GraphDiTPolicy fused kernel for MI355X (gfx950).
// B=32768, N=2, T=4, D=256, H=8, E=2, HD=32, S=8.
// Inputs fp32 (runtime-detected), OUTPUT FP32.
// R5: latency-bound fix — 2 batches/wave (grid 4096), LDS 29.3 KB ->
// 4-5 blocks/CU, transposed score tile (2 shuffles/softmax), fast tanh.

typedef short bf16x8 __attribute__((ext_vector_type(8)));
typedef float f32x4 __attribute__((ext_vector_type(4)));
typedef unsigned short u16;

#define SCALE_F 0.17677669529663687f   // 1/sqrt(32)
#define WT_BYTES (1024 * 256 * 2)      // (768+256) rows x 256 cols x 2B

__device__ __forceinline__ float bf2f(u16 h) {
  unsigned u = ((unsigned)h) << 16; float f; __builtin_memcpy(&f, &u, 4); return f;
}
__device__ __forceinline__ u16 f2bf(float f) {
  unsigned u; __builtin_memcpy(&u, &f, 4);
  u += 0x7FFFu + ((u >> 16) & 1u);
  return (u16)(u >> 16);
}
__device__ __forceinline__ float fast_tanh(float x) {
  // 1 - 2/(e^{2x}+1); exact at +-inf, bf16-accurate elsewhere
  return 1.f - 2.f / (__expf(2.f * x) + 1.f);
}
__device__ __forceinline__ float fast_sigmoid(float x) {
  return 1.f / (1.f + __expf(-x));
}

template<bool F32>
__device__ __forceinline__ float LD(const void* p, int i) {
  if constexpr (F32) return ((const float*)p)[i];
  else return bf2f(((const u16*)p)[i]);
}

template<bool F32>
__device__ __forceinline__ bf16x8 load8bf(const void* p, int idx) {
  if constexpr (F32) {
    const float* f = (const float*)p + idx;
    float4 a = *(const float4*)f;
    float4 b = *(const float4*)(f + 4);
    bf16x8 r;
    r[0] = (short)f2bf(a.x); r[1] = (short)f2bf(a.y);
    r[2] = (short)f2bf(a.z); r[3] = (short)f2bf(a.w);
    r[4] = (short)f2bf(b.x); r[5] = (short)f2bf(b.y);
    r[6] = (short)f2bf(b.z); r[7] = (short)f2bf(b.w);
    return r;
  } else {
    return *(const bf16x8*)((const u16*)p + idx);
  }
}

// fp32-vs-bf16 detection on x's raw u16s (even halves wild for fp32).
__global__ void detect_kernel(const u16* __restrict__ x16, int* __restrict__ flag) {
  __shared__ int tot;
  if (threadIdx.x == 0) tot = 0;
  __syncthreads();
  int cnt = 0;
  for (int i = threadIdx.x; i < 4096; i += 256) {
    int e = (x16[2 * i] >> 7) & 0xFF;
    cnt += (e >= 0x90 || e <= 0x50) ? 1 : 0;
  }
  atomicAdd(&tot, cnt);
  __syncthreads();
  if (threadIdx.x == 0) *flag = (tot >= 64) ? 1 : 0;
}

// Coalesced LDS-tile transpose: WT[(mat*256+n)*256+k] = Wmat[k][n] (bf16).
// mats: 0=Wq 1=Wk 2=Wv 3=Wo. 256 blocks x 256 thr; 32x32 fp32 tiles.
__global__ void prep_kernel(const void* __restrict__ Wq, const void* __restrict__ Wk,
                            const void* __restrict__ Wv, const void* __restrict__ Wo,
                            const int* __restrict__ flag, u16* __restrict__ WT) {
  __shared__ float tile[32][33];
  const bool f32 = (*flag != 0);
  int mat = blockIdx.x >> 6;
  int tl  = blockIdx.x & 63;
  int tn = tl >> 3, tk = tl & 7;
  const void* src = mat == 0 ? Wq : (mat == 1 ? Wk : (mat == 2 ? Wv : Wo));
  int c = threadIdx.x & 31, r0 = threadIdx.x >> 5;
#pragma unroll
  for (int i = 0; i < 4; ++i) {
    int kr = r0 + i * 8;
    int idx = (tk * 32 + kr) * 256 + tn * 32 + c;
    tile[kr][c] = f32 ? ((const float*)src)[idx] : bf2f(((const u16*)src)[idx]);
  }
  __syncthreads();
#pragma unroll
  for (int i = 0; i < 4; ++i) {
    int nr = r0 + i * 8;
    WT[(mat * 256 + tn * 32 + nr) * 256 + tk * 32 + c] = f2bf(tile[c][nr]);
  }
}

struct __align__(16) SharedMem {
  u16 qk[4][16][72];    // [wave][xrow 0-15][Q 0-31 | K 32-63 | pad]
  u16 vt[4][32][32];    // [wave][d][t'], cols 16-31 stay zero
  u16 pb[4][16][32];    // [wave][s][t'], cols 16-31 stay zero
  u16 pooled[16][264];  // [(batch*2+node) block-local][dim]
};

template<bool F32>
__device__ __forceinline__ void fused_impl(
    SharedMem& sm,
    const void* __restrict__ x, const void* __restrict__ edge,
    const void* __restrict__ bq, const void* __restrict__ bk, const void* __restrict__ bv,
    const void* __restrict__ bo,
    const void* __restrict__ Wbias, const void* __restrict__ bbias,
    const void* __restrict__ Wgate, const void* __restrict__ bgate,
    const void* __restrict__ Wscale, const void* __restrict__ bscale,
    const void* __restrict__ Wshift, const void* __restrict__ bshift,
    const void* __restrict__ Whs, const void* __restrict__ bhs,
    const u16* __restrict__ WT, float* __restrict__ out) {
  const int tid = threadIdx.x;
  const int w  = tid >> 6;     // wave 0..3, owns batches w*2, w*2+1
  const int l  = tid & 63;
  const int ln = l & 15;
  const int q4 = l >> 4;       // quad group 0..3

  // zero vt & pb once (cols 16..31 are MFMA K-padding, must stay 0)
  {
    u16* vz = &sm.vt[w][0][0];
#pragma unroll
    for (int i = 0; i < 16; ++i) vz[l + 64 * i] = 0;   // 32*32 = 1024
    u16* pz = &sm.pb[w][0][0];
#pragma unroll
    for (int i = 0; i < 8; ++i) pz[l + 64 * i] = 0;    // 16*32 = 512
  }

  // X rows (16) as MFMA A-fragments: lane holds X[ln][ks*32 + q4*8 + j]
  const int xbase = (blockIdx.x * 64 + w * 16) * 256;
  bf16x8 xa[8];
#pragma unroll
  for (int ks = 0; ks < 8; ++ks)
    xa[ks] = load8bf<F32>(x, xbase + ln * 256 + ks * 32 + q4 * 8);

  // per-wave edge values (2 batches), hoisted out of the head loop
  const int gb0 = blockIdx.x * 8 + w * 2;
  const float e00 = LD<F32>(edge, gb0 * 2),     e01 = LD<F32>(edge, gb0 * 2 + 1);
  const float e10 = LD<F32>(edge, gb0 * 2 + 2), e11 = LD<F32>(edge, gb0 * 2 + 3);
  // this lane's batch (rows q4*4..q4*4+3 all belong to batch q4>>1)
  const float eL0 = (q4 >> 1) ? e10 : e00, eL1 = (q4 >> 1) ? e11 : e01;

#pragma unroll 1
  for (int h = 0; h < 8; ++h) {
    // ---------- QKV GEMM head h: [16 rows] x [96 cols] x K=256 ----------
    f32x4 acc[6];
#pragma unroll
    for (int nt = 0; nt < 6; ++nt) acc[nt] = (f32x4){0.f, 0.f, 0.f, 0.f};

    const u16* wp[6];
#pragma unroll
    for (int nt = 0; nt < 6; ++nt) {
      int nrow = (nt >> 1) * 256 + h * 32 + (nt & 1) * 16 + ln;
      wp[nt] = WT + nrow * 256 + q4 * 8;
    }
#pragma unroll
    for (int ks = 0; ks < 8; ++ks) {
      bf16x8 bfr[6];
#pragma unroll
      for (int nt = 0; nt < 6; ++nt) bfr[nt] = *(const bf16x8*)(wp[nt] + ks * 32);
#pragma unroll
      for (int nt = 0; nt < 6; ++nt)
        acc[nt] = __builtin_amdgcn_mfma_f32_16x16x32_bf16(xa[ks], bfr[nt], acc[nt], 0, 0, 0);
    }

    // ---------- epilogue: Q,K (+bias) row-major to LDS ----------
#pragma unroll
    for (int nt = 0; nt < 4; ++nt) {
      int cb = (nt & 1) * 16 + ln;                       // 0..31 within head
      float bias = LD<F32>((nt >> 1) ? bk : bq, h * 32 + cb);
      int col = (nt >> 1) * 32 + cb;                     // Q: 0-31, K: 32-63
#pragma unroll
      for (int r = 0; r < 4; ++r)
        sm.qk[w][q4 * 4 + r][col] = f2bf(acc[nt][r] + bias);
    }
    // ---------- epilogue: V with edge modulation, stored transposed ----------
#pragma unroll
    for (int nt = 4; nt < 6; ++nt) {
      int dl = (nt - 4) * 16 + ln;                       // head-local dim
      int dg = h * 32 + dl;
      float bvv = LD<F32>(bv, dg);
      float ga = fast_sigmoid(eL0 * LD<F32>(Wgate, dg)  + eL1 * LD<F32>(Wgate, 256 + dg)  + LD<F32>(bgate, dg));
      float sc = fast_tanh(eL0 * LD<F32>(Wscale, dg) + eL1 * LD<F32>(Wscale, 256 + dg) + LD<F32>(bscale, dg));
      float sh = eL0 * LD<F32>(Wshift, dg) + eL1 * LD<F32>(Wshift, 256 + dg) + LD<F32>(bshift, dg);
      u16 vv[4];
#pragma unroll
      for (int r = 0; r < 4; ++r) {
        float v = acc[nt][r] + bvv;
        v = (v * (1.f + sc) + sh) * ga;
        vv[r] = f2bf(v);
      }
      ushort4 pk; pk.x = vv[0]; pk.y = vv[1]; pk.z = vv[2]; pk.w = vv[3];
      *(ushort4*)&sm.vt[w][dl][q4 * 4] = pk;   // vt[d][t'=q4*4+r], 8B aligned
    }
    __asm__ volatile("" ::: "memory");  // wave-private LDS; DS ops in-order

    // ---------- attention: one 16x16 tile (2 batches), TRANSPOSED scores ----------
    float wb0 = LD<F32>(Wbias, h), wb1 = LD<F32>(Wbias, 8 + h), bb  = LD<F32>(bbias, h);
    float wh0 = LD<F32>(Whs, h),   wh1 = LD<F32>(Whs, 8 + h),   bh_ = LD<F32>(bhs, h);
    float eb0 = e00 * wb0 + e01 * wb1 + bb;
    float eb1 = e10 * wb0 + e11 * wb1 + bb;
    float hs0 = fast_tanh(e00 * wh0 + e01 * wh1 + bh_);
    float hs1 = fast_tanh(e10 * wh0 + e11 * wh1 + bh_);
    {
      // A = K rows, B = Q rows -> C[m=t][n=s]; softmax over m (2 shuffles)
      bf16x8 ka = *(const bf16x8*)&sm.qk[w][ln][32 + q4 * 8];
      bf16x8 qb = *(const bf16x8*)&sm.qk[w][ln][q4 * 8];
      f32x4 z4 = {0.f, 0.f, 0.f, 0.f};
      f32x4 s = __builtin_amdgcn_mfma_f32_16x16x32_bf16(ka, qb, z4, 0, 0, 0);

      int sb = ln >> 3;                       // col (s) batch
      bool valid = ((q4 >> 1) == sb);         // row (t) batch == col batch
      float mult = SCALE_F * (1.f + (sb ? hs1 : hs0));
      float ebias = sb ? eb1 : eb0;
      int sl = ln & 7;                        // s within batch
      float p[4];
#pragma unroll
      for (int r = 0; r < 4; ++r) {
        int tl = (q4 & 1) * 4 + r;            // t within batch
        p[r] = s[r] * mult + ((tl == (sl ^ 4)) ? ebias : 0.f);  // sparse bias
      }
      // softmax over t: 4 regs here + 4 in partner lane (l^16)
      float m4 = fmaxf(fmaxf(p[0], p[1]), fmaxf(p[2], p[3]));
      float m = fmaxf(m4, __shfl_xor(m4, 16));
      float s4 = 0.f;
#pragma unroll
      for (int r = 0; r < 4; ++r) { p[r] = __expf(p[r] - m); s4 += p[r]; }
      float su = s4 + __shfl_xor(s4, 16);
      float inv = 1.f / su;
      u16 pv[4];
#pragma unroll
      for (int r = 0; r < 4; ++r) pv[r] = valid ? f2bf(p[r] * inv) : (u16)0;
      ushort4 pk; pk.x = pv[0]; pk.y = pv[1]; pk.z = pv[2]; pk.w = pv[3];
      *(ushort4*)&sm.pb[w][ln][q4 * 4] = pk;   // pb[s][t'=q4*4+r], 8B aligned
      __asm__ volatile("" ::: "memory");

      // P.V via MFMA; lane's 4 C rows = one (batch,node)'s T rows -> free mean
      bf16x8 pa = *(const bf16x8*)&sm.pb[w][ln][q4 * 8];
#pragma unroll
      for (int nt = 0; nt < 2; ++nt) {
        bf16x8 vb = *(const bf16x8*)&sm.vt[w][nt * 16 + ln][q4 * 8];
        f32x4 z = {0.f, 0.f, 0.f, 0.f};
        f32x4 o = __builtin_amdgcn_mfma_f32_16x16x32_bf16(pa, vb, z, 0, 0, 0);
        float pm = (o[0] + o[1] + o[2] + o[3]) * 0.25f;   // mean over T=4
        sm.pooled[w * 4 + q4][h * 32 + nt * 16 + ln] = f2bf(pm);
      }
    }
  }

  // ---------- final projection: pooled[16][256] @ Wo + bo (fp32 out) ----------
  __syncthreads();
  const u16* WoT = WT + 768 * 256;
  f32x4 fo[4];
#pragma unroll
  for (int nt = 0; nt < 4; ++nt) fo[nt] = (f32x4){0.f, 0.f, 0.f, 0.f};
#pragma unroll
  for (int ks = 0; ks < 8; ++ks) {
    bf16x8 af = *(const bf16x8*)&sm.pooled[ln][ks * 32 + q4 * 8];
#pragma unroll
    for (int ntw = 0; ntw < 4; ++ntw) {
      int nrow = w * 64 + ntw * 16 + ln;
      bf16x8 bfr = *(const bf16x8*)(WoT + nrow * 256 + ks * 32 + q4 * 8);
      fo[ntw] = __builtin_amdgcn_mfma_f32_16x16x32_bf16(af, bfr, fo[ntw], 0, 0, 0);
    }
  }
#pragma unroll
  for (int ntw = 0; ntw < 4; ++ntw) {
    int col = w * 64 + ntw * 16 + ln;
    float bias = LD<F32>(bo, col);
#pragma unroll
    for (int r = 0; r < 4; ++r) {
      int row = q4 * 4 + r;                 // block-local batch*2+node
      out[(blockIdx.x * 16 + row) * 256 + col] = fo[ntw][r] + bias;  // FP32
    }
  }
}

__global__ __launch_bounds__(256, 4) void fused_kernel(
    const void* __restrict__ x, const void* __restrict__ edge,
    const void* __restrict__ bq, const void* __restrict__ bk, const void* __restrict__ bv,
    const void* __restrict__ bo,
    const void* __restrict__ Wbias, const void* __restrict__ bbias,
    const void* __restrict__ Wgate, const void* __restrict__ bgate,
    const void* __restrict__ Wscale, const void* __restrict__ bscale,
    const void* __restrict__ Wshift, const void* __restrict__ bshift,
    const void* __restrict__ Whs, const void* __restrict__ bhs,
    const int* __restrict__ flag, const u16* __restrict__ WT, float* __restrict__ out) {
  __shared__ SharedMem sm;
  if (*flag)
    fused_impl<true>(sm, x, edge, bq, bk, bv, bo, Wbias, bbias, Wgate, bgate,
                     Wscale, bscale, Wshift, bshift, Whs, bhs, WT, out);
  else
    fused_impl<false>(sm, x, edge, bq, bk, bv, bo, Wbias, bbias, Wgate, bgate,
                      Wscale, bscale, Wshift, bshift, Whs, bhs, WT, out);
}

extern "C" void kernel_launch(void* const* d_in, const int* in_sizes, int n_in,
                              void* d_out, int out_size, void* d_ws, size_t ws_size,
                              hipStream_t stream) {
  (void)in_sizes; (void)n_in; (void)out_size; (void)ws_size;
  const void* x      = d_in[0];
  const void* edge   = d_in[1];
  const void* Wq     = d_in[2];  const void* bq  = d_in[3];
  const void* Wk     = d_in[4];  const void* bk  = d_in[5];
  const void* Wv     = d_in[6];  const void* bv  = d_in[7];
  const void* Wo     = d_in[8];  const void* bo  = d_in[9];
  const void* Wbias  = d_in[10]; const void* bbias  = d_in[11];
  const void* Wgate  = d_in[12]; const void* bgate  = d_in[13];
  const void* Wscale = d_in[14]; const void* bscale = d_in[15];
  const void* Wshift = d_in[16]; const void* bshift = d_in[17];
  const void* Whs    = d_in[18]; const void* bhs    = d_in[19];
  u16* WT   = (u16*)d_ws;
  int* flag = (int*)((char*)d_ws + WT_BYTES);
  float* out = (float*)d_out;

  detect_kernel<<<1, 256, 0, stream>>>((const u16*)x, flag);
  prep_kernel<<<256, 256, 0, stream>>>(Wq, Wk, Wv, Wo, flag, WT);
  fused_kernel<<<4096, 256, 0, stream>>>(x, edge, bq, bk, bv, bo, Wbias, bbias,
                                         Wgate, bgate, Wscale, bscale, Wshift, bshift,
                                         Whs, bhs, flag, WT, out);
}